// Round 1
// baseline (44.150 us; speedup 1.0000x reference)
//
#include <hip/hip_runtime.h>

// Problem: x [8192, 4096] fp32.
// y = 2x; if row_sum(y) > 10: y -= 1.
// Memory-bound: 256 MiB total traffic -> ~43 us at 6.3 TB/s.

constexpr int ROWS  = 8192;
constexpr int COLS  = 4096;
constexpr int BLOCK = 256;               // 1 block per row
constexpr int VEC_PER_THREAD = COLS / (BLOCK * 4);  // 4 float4 per thread

__global__ __launch_bounds__(BLOCK)
void rowcond_kernel(const float* __restrict__ x, float* __restrict__ out) {
    const int row = blockIdx.x;
    const int tid = threadIdx.x;
    const float* __restrict__ xr = x + (size_t)row * COLS;
    float* __restrict__ orow     = out + (size_t)row * COLS;

    // Load entire row into registers (16 floats/thread), coalesced float4.
    float4 v[VEC_PER_THREAD];
    double s = 0.0;
#pragma unroll
    for (int c = 0; c < VEC_PER_THREAD; ++c) {
        v[c] = reinterpret_cast<const float4*>(xr)[tid + c * BLOCK];
        s += (double)v[c].x + (double)v[c].y + (double)v[c].z + (double)v[c].w;
    }

    // Wave-64 butterfly reduce, then cross-wave via LDS.
    #pragma unroll
    for (int off = 32; off >= 1; off >>= 1)
        s += __shfl_down(s, off, 64);

    __shared__ double wsum[BLOCK / 64];
    __shared__ float  subv;
    const int lane = tid & 63;
    const int wave = tid >> 6;
    if (lane == 0) wsum[wave] = s;
    __syncthreads();
    if (tid == 0) {
        double tot = 0.0;
        #pragma unroll
        for (int w = 0; w < BLOCK / 64; ++w) tot += wsum[w];
        // row_sum(y) = 2 * sum(x); condition: > 10
        subv = (2.0 * tot > 10.0) ? 1.0f : 0.0f;
    }
    __syncthreads();
    const float sub = subv;

    // y = 2x - sub, vectorized stores.
#pragma unroll
    for (int c = 0; c < VEC_PER_THREAD; ++c) {
        float4 o;
        o.x = v[c].x * 2.0f - sub;
        o.y = v[c].y * 2.0f - sub;
        o.z = v[c].z * 2.0f - sub;
        o.w = v[c].w * 2.0f - sub;
        reinterpret_cast<float4*>(orow)[tid + c * BLOCK] = o;
    }
}

extern "C" void kernel_launch(void* const* d_in, const int* in_sizes, int n_in,
                              void* d_out, int out_size, void* d_ws, size_t ws_size,
                              hipStream_t stream) {
    const float* x = (const float*)d_in[0];
    float* out = (float*)d_out;
    rowcond_kernel<<<ROWS, BLOCK, 0, stream>>>(x, out);
}

// Round 3
// 44.044 us; speedup vs baseline: 1.0024x; 1.0024x over previous
//
#include <hip/hip_runtime.h>

// Problem: x [8192, 4096] fp32.
// y = 2x; if row_sum(y) > 10: y -= 1.
// Memory-bound: 256 MiB total traffic -> ~43 us floor at 6.3 TB/s.
// R1: 44.15 us (96.6% of copy ceiling). R3: nontemporal stores via native
// clang vector type (HIP float4 struct is rejected by the builtin).

constexpr int ROWS  = 8192;
constexpr int COLS  = 4096;
constexpr int BLOCK = 256;               // 1 block per row
constexpr int VEC_PER_THREAD = COLS / (BLOCK * 4);  // 4 float4 per thread

typedef float floatx4 __attribute__((ext_vector_type(4)));

__global__ __launch_bounds__(BLOCK)
void rowcond_kernel(const float* __restrict__ x, float* __restrict__ out) {
    const int row = blockIdx.x;
    const int tid = threadIdx.x;
    const float* __restrict__ xr = x + (size_t)row * COLS;
    float* __restrict__ orow     = out + (size_t)row * COLS;

    // Load entire row into registers (16 floats/thread), coalesced 16B loads.
    floatx4 v[VEC_PER_THREAD];
    double s = 0.0;
#pragma unroll
    for (int c = 0; c < VEC_PER_THREAD; ++c) {
        v[c] = reinterpret_cast<const floatx4*>(xr)[tid + c * BLOCK];
        s += (double)v[c].x + (double)v[c].y + (double)v[c].z + (double)v[c].w;
    }

    // Wave-64 butterfly reduce, then cross-wave via LDS.
    #pragma unroll
    for (int off = 32; off >= 1; off >>= 1)
        s += __shfl_down(s, off, 64);

    __shared__ double wsum[BLOCK / 64];
    __shared__ float  subv;
    const int lane = tid & 63;
    const int wave = tid >> 6;
    if (lane == 0) wsum[wave] = s;
    __syncthreads();
    if (tid == 0) {
        double tot = 0.0;
        #pragma unroll
        for (int w = 0; w < BLOCK / 64; ++w) tot += wsum[w];
        // row_sum(y) = 2 * sum(x); condition: > 10
        subv = (2.0 * tot > 10.0) ? 1.0f : 0.0f;
    }
    __syncthreads();
    const float sub = subv;

    // y = 2x - sub, vectorized nontemporal stores (write stream is never
    // re-read; keep it out of L2/L3 so the input stays resident).
#pragma unroll
    for (int c = 0; c < VEC_PER_THREAD; ++c) {
        floatx4 o = v[c] * 2.0f - sub;
        __builtin_nontemporal_store(o, &reinterpret_cast<floatx4*>(orow)[tid + c * BLOCK]);
    }
}

extern "C" void kernel_launch(void* const* d_in, const int* in_sizes, int n_in,
                              void* d_out, int out_size, void* d_ws, size_t ws_size,
                              hipStream_t stream) {
    const float* x = (const float*)d_in[0];
    float* out = (float*)d_out;
    rowcond_kernel<<<ROWS, BLOCK, 0, stream>>>(x, out);
}